// Round 7
// baseline (242.769 us; speedup 1.0000x reference)
//
#include <hip/hip_runtime.h>
#include <hip/hip_bf16.h>

typedef unsigned short u16;
typedef __attribute__((ext_vector_type(8))) short bf16x8;
typedef __attribute__((ext_vector_type(4))) float f32x4;

#define SEQ_L 4096
#define M_TOT 16384   // B*L

__device__ __forceinline__ float bf2f(u16 x) {
    unsigned u = ((unsigned)x) << 16;
    return __builtin_bit_cast(float, u);
}
__device__ __forceinline__ u16 f2bf(float f) {
    unsigned u = __builtin_bit_cast(unsigned, f);
    u += 0x7FFFu + ((u >> 16) & 1u);   // round-to-nearest-even
    return (u16)(u >> 16);
}
// async 16B global->LDS (direct-to-LDS DMA; LDS dest = uniform base + lane*16)
__device__ __forceinline__ void gload16(const u16* g, u16* l) {
    __builtin_amdgcn_global_load_lds(
        (const __attribute__((address_space(1))) unsigned int*)g,
        (__attribute__((address_space(3))) unsigned int*)l, 16, 0, 0);
}

// ---- prep_all: pack six fp32 inputs -> x bf16 | Wqkv,Wout -> bf16 | mask compact ----
// id layout: [0,1572864) pack (which=id>>18), [..+73728) Wqkv, [..+8192) Wout, [..+4096) mask
__global__ __launch_bounds__(256) void prep_all(
    const float* __restrict__ in0, const float* __restrict__ in1, const float* __restrict__ in2,
    const float* __restrict__ in3, const float* __restrict__ in4, const float* __restrict__ in5,
    const float* __restrict__ Wqkv, const float* __restrict__ Wout, const void* __restrict__ mask,
    u16* __restrict__ x, u16* __restrict__ Wqkv_bf, u16* __restrict__ Wout_bf,
    unsigned char* __restrict__ cmask) {
    int id = blockIdx.x * 256 + threadIdx.x;
    if (id < 1572864) {
        const float* ins[6] = {in0, in1, in2, in3, in4, in5};
        int which = id >> 18, j = id & 262143;
        int m = j >> 4, c8 = j & 15;
        const float* sp = ins[which] + (size_t)m * 128 + c8 * 8;
        float4 a = *(const float4*)sp;
        float4 b = *(const float4*)(sp + 4);
        u16 t[8] = {f2bf(a.x), f2bf(a.y), f2bf(a.z), f2bf(a.w),
                    f2bf(b.x), f2bf(b.y), f2bf(b.z), f2bf(b.w)};
        *(uint4*)(x + (size_t)m * 768 + which * 128 + c8 * 8) = *(uint4*)t;
    } else if (id < 1572864 + 73728 + 8192) {
        int i = id - 1572864;
        const float* src = (i < 73728) ? Wqkv : Wout;
        u16* dst = (i < 73728) ? Wqkv_bf : Wout_bf;
        if (i >= 73728) i -= 73728;
        const float* sp = src + (size_t)i * 8;
        float4 a = *(const float4*)sp;
        float4 b = *(const float4*)(sp + 4);
        u16 t[8] = {f2bf(a.x), f2bf(a.y), f2bf(a.z), f2bf(a.w),
                    f2bf(b.x), f2bf(b.y), f2bf(b.z), f2bf(b.w)};
        *(uint4*)(dst + (size_t)i * 8) = *(uint4*)t;
    } else if (id < 1572864 + 73728 + 8192 + 4096) {
        int i = id - 1572864 - 73728 - 8192;
        int bi = i >> 6, bj = i & 63;
        size_t e = (size_t)(bi * 64) * SEQ_L + (size_t)bj * 64;
        const unsigned char* p8 = (const unsigned char*)mask;
        unsigned w0 = *(const unsigned*)mask;   // [0][0],[0][1] always true -> fingerprint
        bool v;
        if (w0 == 0x01010101u || w0 == 0xFFFFFFFFu)      v = p8[e] != 0;
        else if (w0 == 0x3F803F80u || w0 == 0x3C003C00u) v = ((const u16*)mask)[e] != 0;
        else                                             v = ((const unsigned*)mask)[e] != 0;
        cmask[i] = v ? 1 : 0;
    }
}

// ---------------- QKV GEMM, 128x128 tile, async staging + XOR swizzle ----------------
__global__ __launch_bounds__(256) void qkv_gemm(
    const u16* __restrict__ X, const u16* __restrict__ W, const float* __restrict__ bias,
    u16* __restrict__ qk, u16* __restrict__ vt) {
    __shared__ __align__(16) u16 As[128 * 64];
    __shared__ __align__(16) u16 Bs[128 * 64];
    int m0 = blockIdx.x * 128, n0 = blockIdx.y * 128;
    int tid = threadIdx.x, lane = tid & 63, w = tid >> 6;
    int ln = lane & 15, quad = lane >> 4;
    int rw = (w >> 1) * 64, cw = (w & 1) * 64;
    int lr8 = lane >> 3, lc = lane & 7;
    int swz_st = lc ^ (lr8 & 7);
    f32x4 acc[4][4] = {};
    for (int kk = 0; kk < 768; kk += 64) {
        __syncthreads();
        #pragma unroll
        for (int j = 0; j < 4; j++) {
            int r0 = w * 32 + j * 8;
            int r = r0 + lr8;
            gload16(X + (size_t)(m0 + r) * 768 + kk + swz_st * 8, As + r0 * 64 + lane * 8);
            gload16(W + (size_t)(n0 + r) * 768 + kk + swz_st * 8, Bs + r0 * 64 + lane * 8);
        }
        __syncthreads();
        #pragma unroll
        for (int s = 0; s < 2; s++) {
            bf16x8 af[4], bfr[4];
            #pragma unroll
            for (int i = 0; i < 4; i++) {
                int R = rw + i * 16 + ln;
                af[i] = *(const bf16x8*)(As + R * 64 + ((4 * s + quad) ^ (ln & 7)) * 8);
            }
            #pragma unroll
            for (int t = 0; t < 4; t++) {
                int R = cw + t * 16 + ln;
                bfr[t] = *(const bf16x8*)(Bs + R * 64 + ((4 * s + quad) ^ (ln & 7)) * 8);
            }
            #pragma unroll
            for (int i = 0; i < 4; i++)
                #pragma unroll
                for (int t = 0; t < 4; t++)
                    acc[i][t] = __builtin_amdgcn_mfma_f32_16x16x32_bf16(af[i], bfr[t], acc[i][t], 0, 0, 0);
        }
    }
    #pragma unroll
    for (int i = 0; i < 4; i++) {
        int row0 = m0 + rw + i * 16 + 4 * quad;
        #pragma unroll
        for (int t = 0; t < 4; t++) {
            int col = n0 + cw + t * 16 + ln;
            float bv = bias[col];
            if (col < 512) {
                #pragma unroll
                for (int r = 0; r < 4; r++)
                    qk[(size_t)(row0 + r) * 512 + col] = f2bf(acc[i][t][r] + bv);
            } else {
                int d = col - 512;
                int b = row0 >> 12, seq = row0 & 4095;
                u16 pk[4] = {f2bf(acc[i][t][0] + bv), f2bf(acc[i][t][1] + bv),
                             f2bf(acc[i][t][2] + bv), f2bf(acc[i][t][3] + bv)};
                *(ushort4*)(vt + ((size_t)(b * 2 + (d >> 7)) * 128 + (d & 127)) * SEQ_L + seq)
                    = *(ushort4*)pk;
            }
        }
    }
}

// ---- fused block-sparse flash attention (both channels) + output projection ----
// One block per (b, q-block). Phase A: per channel c, flash attention over active
// k-blocks (async double-buffered K/V staging), O/l written to Ao[64][256].
// Phase B: out[64,256] = Ao @ Wout^T + bias, streamed over k in 4 chunks.
__global__ __launch_bounds__(256) void attn_out(
    const u16* __restrict__ qk, const u16* __restrict__ vt, const u16* __restrict__ Wout,
    const unsigned char* __restrict__ cmask, const float* __restrict__ bout,
    float* __restrict__ out) {
    __shared__ __align__(16) u16 Ks[2][64 * 128];   // also reused as Bs (32 KB) in phase B
    __shared__ __align__(16) u16 Vt[2][128 * 64];
    __shared__ __align__(16) u16 Ps[4][16 * 72];
    __shared__ __align__(16) u16 Ao[64 * 264];      // A-buffer, stride 264: conflict-free frags

    int idx = blockIdx.x;
    int qi = 63 - (idx >> 2);          // heavy q-blocks first
    int b = idx & 3;
    int tid = threadIdx.x, lane = tid & 63, w = tid >> 6;
    int ln = lane & 15, quad = lane >> 4;
    const float scale = 0.08838834764831845f;  // 1/sqrt(128)

    int k_lr = lane >> 4, k_lc = lane & 15;
    int v_lr = lane >> 3, v_lc = lane & 7;

    // active-block bitmap (built once)
    const unsigned char* mrow = cmask + qi * 64;
    unsigned long long bm0 = 0;
    for (int k = 0; k <= qi; k++) bm0 |= (unsigned long long)(mrow[k] != 0) << k;

    for (int c = 0; c < 2; c++) {
        const u16* kb_base = qk + (size_t)b * SEQ_L * 512 + 256 + c * 128;
        const u16* vt_base = vt + (size_t)(b * 2 + c) * 128 * SEQ_L;

        // Q fragments: A[m=ln][k=32s+8*quad+j]
        bf16x8 qf[4];
        {
            size_t grow = (size_t)(b * SEQ_L + qi * 64 + w * 16 + ln);
            const u16* qp = qk + grow * 512 + c * 128;
            #pragma unroll
            for (int s = 0; s < 4; s++) qf[s] = *(const bf16x8*)(qp + 32 * s + 8 * quad);
        }
        float m_st[4], l_st[4];
        #pragma unroll
        for (int r = 0; r < 4; r++) { m_st[r] = -1e30f; l_st[r] = 0.f; }
        f32x4 accO[8] = {};

        unsigned long long bm = bm0;
        int cur = __ffsll(bm) - 1; bm &= bm - 1;
        int buf = 0;
        __syncthreads();   // WAR: prior channel's last K/V reads done before restage
        {
            const u16* kp = kb_base + (size_t)cur * 64 * 512;
            const u16* vp = vt_base + cur * 64;
            #pragma unroll
            for (int j = 0; j < 4; j++) {
                int kr0 = w * 16 + j * 4, kr = kr0 + k_lr;
                gload16(kp + (size_t)kr * 512 + (k_lc ^ (kr & 7)) * 8, Ks[0] + kr0 * 128 + lane * 8);
                int vr0 = w * 32 + j * 8, vr = vr0 + v_lr;
                gload16(vp + (size_t)vr * SEQ_L + (v_lc ^ (vr & 7)) * 8, Vt[0] + vr0 * 64 + lane * 8);
            }
        }
        while (cur >= 0) {
            int nxt = bm ? (__ffsll(bm) - 1) : -1;
            if (bm) bm &= bm - 1;
            __syncthreads();   // drains cur's loads; WAR-protects buf^1
            if (nxt >= 0) {
                const u16* kp = kb_base + (size_t)nxt * 64 * 512;
                const u16* vp = vt_base + nxt * 64;
                #pragma unroll
                for (int j = 0; j < 4; j++) {
                    int kr0 = w * 16 + j * 4, kr = kr0 + k_lr;
                    gload16(kp + (size_t)kr * 512 + (k_lc ^ (kr & 7)) * 8, Ks[buf ^ 1] + kr0 * 128 + lane * 8);
                    int vr0 = w * 32 + j * 8, vr = vr0 + v_lr;
                    gload16(vp + (size_t)vr * SEQ_L + (v_lc ^ (vr & 7)) * 8, Vt[buf ^ 1] + vr0 * 64 + lane * 8);
                }
            }

            // S = Q K^T
            f32x4 accS[4] = {};
            #pragma unroll
            for (int s = 0; s < 4; s++) {
                #pragma unroll
                for (int t = 0; t < 4; t++) {
                    int R = t * 16 + ln;
                    bf16x8 bfr = *(const bf16x8*)(Ks[buf] + R * 128 + ((4 * s + quad) ^ (ln & 7)) * 8);
                    accS[t] = __builtin_amdgcn_mfma_f32_16x16x32_bf16(qf[s], bfr, accS[t], 0, 0, 0);
                }
            }
            // online softmax
            float P[4][4];
            #pragma unroll
            for (int r = 0; r < 4; r++) {
                float sv[4];
                float mx = -1e30f;
                #pragma unroll
                for (int t = 0; t < 4; t++) { sv[t] = accS[t][r] * scale; mx = fmaxf(mx, sv[t]); }
                #pragma unroll
                for (int off = 1; off < 16; off <<= 1) mx = fmaxf(mx, __shfl_xor(mx, off, 64));
                float nm = fmaxf(m_st[r], mx);
                float alpha = __expf(m_st[r] - nm);
                m_st[r] = nm;
                float rs = 0.f;
                #pragma unroll
                for (int t = 0; t < 4; t++) { float p = __expf(sv[t] - nm); P[t][r] = p; rs += p; }
                #pragma unroll
                for (int off = 1; off < 16; off <<= 1) rs += __shfl_xor(rs, off, 64);
                l_st[r] = l_st[r] * alpha + rs;
                #pragma unroll
                for (int nt = 0; nt < 8; nt++) accO[nt][r] *= alpha;
            }
            // P: C/D -> A-operand layout via wave-private LDS
            #pragma unroll
            for (int t = 0; t < 4; t++)
                #pragma unroll
                for (int r = 0; r < 4; r++)
                    Ps[w][(4 * quad + r) * 72 + ln + 16 * t] = f2bf(P[t][r]);
            // O += P V
            #pragma unroll
            for (int s2 = 0; s2 < 2; s2++) {
                bf16x8 pf = *(const bf16x8*)(&Ps[w][ln * 72 + 32 * s2 + 8 * quad]);
                #pragma unroll
                for (int nt = 0; nt < 8; nt++) {
                    int R = nt * 16 + ln;
                    bf16x8 vf = *(const bf16x8*)(Vt[buf] + R * 64 + ((4 * s2 + quad) ^ (ln & 7)) * 8);
                    accO[nt] = __builtin_amdgcn_mfma_f32_16x16x32_bf16(pf, vf, accO[nt], 0, 0, 0);
                }
            }
            cur = nxt; buf ^= 1;
        }
        // write O/l to Ao (wave-private rows, no barrier)
        float inv[4];
        #pragma unroll
        for (int r = 0; r < 4; r++) inv[r] = 1.0f / fmaxf(l_st[r], 1e-20f);
        #pragma unroll
        for (int nt = 0; nt < 8; nt++)
            #pragma unroll
            for (int r = 0; r < 4; r++)
                Ao[(w * 16 + 4 * quad + r) * 264 + c * 128 + nt * 16 + ln]
                    = f2bf(accO[nt][r] * inv[r]);
    }

    // -------- phase B: out[64,256] = Ao @ Wout^T + bias --------
    u16* Bs = Ks[0];   // 256x64 u16 = 32 KB (reuse)
    f32x4 oacc[4][4] = {};
    for (int kk = 0; kk < 4; kk++) {
        __syncthreads();   // WAR on Bs (and, first iter, Ao write visibility)
        #pragma unroll
        for (int j = 0; j < 8; j++) {
            int o0 = w * 64 + j * 8;
            int o = o0 + (lane >> 3);
            gload16(Wout + (size_t)o * 256 + kk * 64 + (((lane & 7) ^ (o & 7)) * 8),
                    Bs + o0 * 64 + lane * 8);
        }
        __syncthreads();   // drain
        #pragma unroll
        for (int s = 0; s < 2; s++) {
            bf16x8 af[4], bfr[4];
            #pragma unroll
            for (int i = 0; i < 4; i++)
                af[i] = *(const bf16x8*)(Ao + (i * 16 + ln) * 264 + kk * 64 + 32 * s + 8 * quad);
            #pragma unroll
            for (int t = 0; t < 4; t++) {
                int o = w * 64 + t * 16 + ln;
                bfr[t] = *(const bf16x8*)(Bs + o * 64 + ((4 * s + quad) ^ (ln & 7)) * 8);
            }
            #pragma unroll
            for (int i = 0; i < 4; i++)
                #pragma unroll
                for (int t = 0; t < 4; t++)
                    oacc[i][t] = __builtin_amdgcn_mfma_f32_16x16x32_bf16(af[i], bfr[t], oacc[i][t], 0, 0, 0);
        }
    }
    const size_t half = (size_t)M_TOT * 128;
    #pragma unroll
    for (int t = 0; t < 4; t++) {
        int o = w * 64 + t * 16 + ln;
        float bv = bout[o];
        float* base = (o < 128) ? (out + o) : (out + half + (o - 128));
        #pragma unroll
        for (int i = 0; i < 4; i++) {
            int row = b * SEQ_L + qi * 64 + i * 16 + 4 * quad;
            #pragma unroll
            for (int r = 0; r < 4; r++)
                base[(size_t)(row + r) * 128] = oacc[i][t][r] + bv;
        }
    }
}

extern "C" void kernel_launch(void* const* d_in, const int* in_sizes, int n_in,
                              void* d_out, int out_size, void* d_ws, size_t ws_size,
                              hipStream_t stream) {
    char* ws = (char*)d_ws;
    u16* x_bf    = (u16*)ws;                          // 16384*768  = 25.2 MB
    u16* qk_buf  = x_bf + (size_t)M_TOT * 768;        // 16384*512  = 16.8 MB
    u16* vt_buf  = qk_buf + (size_t)M_TOT * 512;      // 1024*4096  =  8.4 MB
    u16* Wqkv_bf = vt_buf + (size_t)1024 * SEQ_L;     // 589824
    u16* Wout_bf = Wqkv_bf + 589824;                  // 65536
    unsigned char* cmask = (unsigned char*)(Wout_bf + 65536);

    hipLaunchKernelGGL(prep_all, dim3(6480), dim3(256), 0, stream,
                       (const float*)d_in[0], (const float*)d_in[1], (const float*)d_in[2],
                       (const float*)d_in[3], (const float*)d_in[4], (const float*)d_in[5],
                       (const float*)d_in[6], (const float*)d_in[8], d_in[10],
                       x_bf, Wqkv_bf, Wout_bf, cmask);
    hipLaunchKernelGGL(qkv_gemm, dim3(128, 6), dim3(256), 0, stream,
                       x_bf, Wqkv_bf, (const float*)d_in[7], qk_buf, vt_buf);
    hipLaunchKernelGGL(attn_out, dim3(256), dim3(256), 0, stream,
                       qk_buf, vt_buf, Wout_bf, cmask, (const float*)d_in[9], (float*)d_out);
}

// Round 8
// 219.697 us; speedup vs baseline: 1.1050x; 1.1050x over previous
//
#include <hip/hip_runtime.h>
#include <hip/hip_bf16.h>

typedef unsigned short u16;
typedef __attribute__((ext_vector_type(8))) short bf16x8;
typedef __attribute__((ext_vector_type(4))) float f32x4;

#define SEQ_L 4096
#define M_TOT 16384   // B*L

__device__ __forceinline__ float bf2f(u16 x) {
    unsigned u = ((unsigned)x) << 16;
    return __builtin_bit_cast(float, u);
}
__device__ __forceinline__ u16 f2bf(float f) {
    unsigned u = __builtin_bit_cast(unsigned, f);
    u += 0x7FFFu + ((u >> 16) & 1u);   // round-to-nearest-even
    return (u16)(u >> 16);
}
// async 16B global->LDS (direct-to-LDS DMA; LDS dest = wave-uniform base + lane*16)
__device__ __forceinline__ void gload16(const u16* g, u16* l) {
    __builtin_amdgcn_global_load_lds(
        (const __attribute__((address_space(1))) unsigned int*)g,
        (__attribute__((address_space(3))) unsigned int*)l, 16, 0, 0);
}

// ---- prep_all: pack six fp32 inputs -> x bf16 | Wqkv,Wout -> bf16 | mask compact ----
__global__ __launch_bounds__(256) void prep_all(
    const float* __restrict__ in0, const float* __restrict__ in1, const float* __restrict__ in2,
    const float* __restrict__ in3, const float* __restrict__ in4, const float* __restrict__ in5,
    const float* __restrict__ Wqkv, const float* __restrict__ Wout, const void* __restrict__ mask,
    u16* __restrict__ x, u16* __restrict__ Wqkv_bf, u16* __restrict__ Wout_bf,
    unsigned char* __restrict__ cmask) {
    int id = blockIdx.x * 256 + threadIdx.x;
    if (id < 1572864) {
        const float* ins[6] = {in0, in1, in2, in3, in4, in5};
        int which = id >> 18, j = id & 262143;
        int m = j >> 4, c8 = j & 15;
        const float* sp = ins[which] + (size_t)m * 128 + c8 * 8;
        float4 a = *(const float4*)sp;
        float4 b = *(const float4*)(sp + 4);
        u16 t[8] = {f2bf(a.x), f2bf(a.y), f2bf(a.z), f2bf(a.w),
                    f2bf(b.x), f2bf(b.y), f2bf(b.z), f2bf(b.w)};
        *(uint4*)(x + (size_t)m * 768 + which * 128 + c8 * 8) = *(uint4*)t;
    } else if (id < 1572864 + 73728 + 8192) {
        int i = id - 1572864;
        const float* src = (i < 73728) ? Wqkv : Wout;
        u16* dst = (i < 73728) ? Wqkv_bf : Wout_bf;
        if (i >= 73728) i -= 73728;
        const float* sp = src + (size_t)i * 8;
        float4 a = *(const float4*)sp;
        float4 b = *(const float4*)(sp + 4);
        u16 t[8] = {f2bf(a.x), f2bf(a.y), f2bf(a.z), f2bf(a.w),
                    f2bf(b.x), f2bf(b.y), f2bf(b.z), f2bf(b.w)};
        *(uint4*)(dst + (size_t)i * 8) = *(uint4*)t;
    } else if (id < 1572864 + 73728 + 8192 + 4096) {
        int i = id - 1572864 - 73728 - 8192;
        int bi = i >> 6, bj = i & 63;
        size_t e = (size_t)(bi * 64) * SEQ_L + (size_t)bj * 64;
        const unsigned char* p8 = (const unsigned char*)mask;
        unsigned w0 = *(const unsigned*)mask;   // [0][0],[0][1] always true -> fingerprint
        bool v;
        if (w0 == 0x01010101u || w0 == 0xFFFFFFFFu)      v = p8[e] != 0;
        else if (w0 == 0x3F803F80u || w0 == 0x3C003C00u) v = ((const u16*)mask)[e] != 0;
        else                                             v = ((const unsigned*)mask)[e] != 0;
        cmask[i] = v ? 1 : 0;
    }
}

// ---------------- QKV GEMM, 128x64 tile (grid 1536 = 6 blocks/CU) ----------------
__global__ __launch_bounds__(256, 4) void qkv_gemm(
    const u16* __restrict__ X, const u16* __restrict__ W, const float* __restrict__ bias,
    u16* __restrict__ qk, u16* __restrict__ vt) {
    __shared__ __align__(16) u16 As[128 * 64];   // 16 KB
    __shared__ __align__(16) u16 Bs[64 * 64];    //  8 KB
    int m0 = blockIdx.x * 128, n0 = blockIdx.y * 64;
    int tid = threadIdx.x, lane = tid & 63, w = tid >> 6;
    int ln = lane & 15, quad = lane >> 4;
    int rw = (w >> 1) * 64, cw = (w & 1) * 32;
    int lr8 = lane >> 3, lc = lane & 7;
    f32x4 acc[4][2] = {};
    for (int kk = 0; kk < 768; kk += 64) {
        __syncthreads();   // WAR
        #pragma unroll
        for (int j = 0; j < 4; j++) {
            int r0 = w * 32 + j * 8, r = r0 + lr8;
            gload16(X + (size_t)(m0 + r) * 768 + kk + ((lc ^ (r & 7)) * 8), As + r0 * 64 + lane * 8);
        }
        #pragma unroll
        for (int j = 0; j < 2; j++) {
            int r0 = w * 16 + j * 8, r = r0 + lr8;
            gload16(W + (size_t)(n0 + r) * 768 + kk + ((lc ^ (r & 7)) * 8), Bs + r0 * 64 + lane * 8);
        }
        __syncthreads();   // drain
        #pragma unroll
        for (int s = 0; s < 2; s++) {
            bf16x8 af[4], bfr[2];
            #pragma unroll
            for (int i = 0; i < 4; i++) {
                int R = rw + i * 16 + ln;
                af[i] = *(const bf16x8*)(As + R * 64 + ((4 * s + quad) ^ (ln & 7)) * 8);
            }
            #pragma unroll
            for (int t = 0; t < 2; t++) {
                int R = cw + t * 16 + ln;
                bfr[t] = *(const bf16x8*)(Bs + R * 64 + ((4 * s + quad) ^ (ln & 7)) * 8);
            }
            #pragma unroll
            for (int i = 0; i < 4; i++)
                #pragma unroll
                for (int t = 0; t < 2; t++)
                    acc[i][t] = __builtin_amdgcn_mfma_f32_16x16x32_bf16(af[i], bfr[t], acc[i][t], 0, 0, 0);
        }
    }
    #pragma unroll
    for (int i = 0; i < 4; i++) {
        int row0 = m0 + rw + i * 16 + 4 * quad;
        #pragma unroll
        for (int t = 0; t < 2; t++) {
            int col = n0 + cw + t * 16 + ln;
            float bv = bias[col];
            if (col < 512) {   // block-uniform (n0 is 64-aligned)
                #pragma unroll
                for (int r = 0; r < 4; r++)
                    qk[(size_t)(row0 + r) * 512 + col] = f2bf(acc[i][t][r] + bv);
            } else {
                int d = col - 512;
                int b = row0 >> 12, seq = row0 & 4095;
                u16 pk[4] = {f2bf(acc[i][t][0] + bv), f2bf(acc[i][t][1] + bv),
                             f2bf(acc[i][t][2] + bv), f2bf(acc[i][t][3] + bv)};
                *(ushort4*)(vt + ((size_t)(b * 2 + (d >> 7)) * 128 + (d & 127)) * SEQ_L + seq)
                    = *(ushort4*)pk;
            }
        }
    }
}

// ---- fused attention + out-proj: one block per (b, q-block, 32-row half) ----
// 4 waves: waves 0-1 = channel 0 (rows 0-15 / 16-31), waves 2-3 = channel 1.
// Channels run IN PARALLEL; K/V single-buffered per channel; LDS exactly 80 KiB
// so 2 blocks/CU co-reside for load balancing.
__global__ __launch_bounds__(256) void attn_out(
    const u16* __restrict__ qk, const u16* __restrict__ vt, const u16* __restrict__ Wout,
    const unsigned char* __restrict__ cmask, const float* __restrict__ bout,
    float* __restrict__ out) {
    __shared__ __align__(16) u16 Ks[2][64 * 128];   // [channel][key][d]; reused as Bs in phase B
    __shared__ __align__(16) u16 Vt[2][128 * 64];   // [channel][d][key]
    __shared__ __align__(16) u16 PsAo[32 * 256];    // union: Ps (4x16x72) during loop / Ao[32][256] after

    int idx = blockIdx.x;
    int qi = 63 - (idx >> 3);          // heavy q-rows first
    int b = (idx >> 1) & 3, half = idx & 1;
    int tid = threadIdx.x, lane = tid & 63, w = tid >> 6;
    int ln = lane & 15, quad = lane >> 4;
    int cw = w >> 1, wr = w & 1;       // channel, 16-row tile within the 32-row half
    const float scale = 0.08838834764831845f;  // 1/sqrt(128)

    const unsigned char* mrow = cmask + qi * 64;
    unsigned long long bm = 0;
    for (int k = 0; k <= qi; k++) bm |= (unsigned long long)(mrow[k] != 0) << k;

    const u16* kb_base = qk + (size_t)b * SEQ_L * 512 + 256 + cw * 128;
    const u16* vt_base = vt + (size_t)(b * 2 + cw) * 128 * SEQ_L;

    // Q fragments: A[m=ln][k=32s+8*quad+j]
    bf16x8 qf[4];
    {
        size_t grow = (size_t)(b * SEQ_L + qi * 64 + half * 32 + wr * 16 + ln);
        const u16* qp = qk + grow * 512 + cw * 128;
        #pragma unroll
        for (int s = 0; s < 4; s++) qf[s] = *(const bf16x8*)(qp + 32 * s + 8 * quad);
    }
    float m_st[4], l_st[4];
    #pragma unroll
    for (int r = 0; r < 4; r++) { m_st[r] = -1e30f; l_st[r] = 0.f; }
    f32x4 accO[8] = {};
    u16* Ps = PsAo + w * 1152;   // wave-private 16x72

    while (bm) {
        int cur = __ffsll(bm) - 1; bm &= bm - 1;
        __syncthreads();   // WAR: prior iter's K/V reads done
        {   // stage this wave's channel: K (8 calls x 4 rows), V^T (8 calls x 8 d-rows)
            const u16* kp = kb_base + (size_t)cur * 64 * 512;
            const u16* vp = vt_base + cur * 64;
            #pragma unroll
            for (int j = 0; j < 8; j++) {
                int kr0 = j * 8 + wr * 4, kr = kr0 + (lane >> 4);
                gload16(kp + (size_t)kr * 512 + (((lane & 15) ^ (kr & 7)) * 8),
                        Ks[cw] + kr0 * 128 + lane * 8);
                int d0 = j * 16 + wr * 8, d = d0 + (lane >> 3);
                gload16(vp + (size_t)d * SEQ_L + (((lane & 7) ^ (d & 7)) * 8),
                        Vt[cw] + d0 * 64 + lane * 8);
            }
        }
        __syncthreads();   // drain

        // S = Q K^T : D[m=4*quad+r][n=ln+16t]
        f32x4 accS[4] = {};
        #pragma unroll
        for (int s = 0; s < 4; s++) {
            #pragma unroll
            for (int t = 0; t < 4; t++) {
                int R = t * 16 + ln;
                bf16x8 bfr = *(const bf16x8*)(Ks[cw] + R * 128 + ((4 * s + quad) ^ (ln & 7)) * 8);
                accS[t] = __builtin_amdgcn_mfma_f32_16x16x32_bf16(qf[s], bfr, accS[t], 0, 0, 0);
            }
        }
        // online softmax per row m = 4*quad + r
        float P[4][4];
        #pragma unroll
        for (int r = 0; r < 4; r++) {
            float sv[4];
            float mx = -1e30f;
            #pragma unroll
            for (int t = 0; t < 4; t++) { sv[t] = accS[t][r] * scale; mx = fmaxf(mx, sv[t]); }
            #pragma unroll
            for (int off = 1; off < 16; off <<= 1) mx = fmaxf(mx, __shfl_xor(mx, off, 64));
            float nm = fmaxf(m_st[r], mx);
            float alpha = __expf(m_st[r] - nm);
            m_st[r] = nm;
            float rs = 0.f;
            #pragma unroll
            for (int t = 0; t < 4; t++) { float p = __expf(sv[t] - nm); P[t][r] = p; rs += p; }
            #pragma unroll
            for (int off = 1; off < 16; off <<= 1) rs += __shfl_xor(rs, off, 64);
            l_st[r] = l_st[r] * alpha + rs;
            #pragma unroll
            for (int nt = 0; nt < 8; nt++) accO[nt][r] *= alpha;
        }
        // P: C/D -> A-operand layout via wave-private LDS
        #pragma unroll
        for (int t = 0; t < 4; t++)
            #pragma unroll
            for (int r = 0; r < 4; r++)
                Ps[(4 * quad + r) * 72 + ln + 16 * t] = f2bf(P[t][r]);
        // O += P V
        #pragma unroll
        for (int s2 = 0; s2 < 2; s2++) {
            bf16x8 pf = *(const bf16x8*)(Ps + ln * 72 + 32 * s2 + 8 * quad);
            #pragma unroll
            for (int nt = 0; nt < 8; nt++) {
                int R = nt * 16 + ln;
                bf16x8 vf = *(const bf16x8*)(Vt[cw] + R * 64 + ((4 * s2 + quad) ^ (ln & 7)) * 8);
                accO[nt] = __builtin_amdgcn_mfma_f32_16x16x32_bf16(pf, vf, accO[nt], 0, 0, 0);
            }
        }
    }

    __syncthreads();   // all Ps dead before Ao overwrites the union
    {   // Ao[32][256] <- O / l  (rows wr*16.., cols cw*128..)
        float inv[4];
        #pragma unroll
        for (int r = 0; r < 4; r++) inv[r] = 1.0f / fmaxf(l_st[r], 1e-20f);
        #pragma unroll
        for (int nt = 0; nt < 8; nt++)
            #pragma unroll
            for (int r = 0; r < 4; r++)
                PsAo[(wr * 16 + 4 * quad + r) * 256 + cw * 128 + nt * 16 + ln]
                    = f2bf(accO[nt][r] * inv[r]);
    }

    // -------- phase B: out[32,256] = Ao @ Wout^T + bias, k streamed in 4 chunks --------
    u16* Bs = Ks[0];   // 256 (out cols) x 64 (k) u16 = 32 KB
    f32x4 oacc[2][4] = {};
    for (int kk = 0; kk < 4; kk++) {
        __syncthreads();   // Ao visibility (kk=0) / WAR on Bs
        #pragma unroll
        for (int j = 0; j < 8; j++) {
            int o0 = w * 64 + j * 8, o = o0 + (lane >> 3);
            gload16(Wout + (size_t)o * 256 + kk * 64 + (((lane & 7) ^ (o & 7)) * 8),
                    Bs + o0 * 64 + lane * 8);
        }
        __syncthreads();   // drain
        #pragma unroll
        for (int s = 0; s < 2; s++) {
            bf16x8 af[2], bfr[4];
            #pragma unroll
            for (int i = 0; i < 2; i++)
                af[i] = *(const bf16x8*)(PsAo + (i * 16 + ln) * 256 + kk * 64 + 32 * s + 8 * quad);
            #pragma unroll
            for (int t = 0; t < 4; t++) {
                int o = w * 64 + t * 16 + ln;
                bfr[t] = *(const bf16x8*)(Bs + o * 64 + ((4 * s + quad) ^ (ln & 7)) * 8);
            }
            #pragma unroll
            for (int i = 0; i < 2; i++)
                #pragma unroll
                for (int t = 0; t < 4; t++)
                    oacc[i][t] = __builtin_amdgcn_mfma_f32_16x16x32_bf16(af[i], bfr[t], oacc[i][t], 0, 0, 0);
        }
    }
    const size_t hlf = (size_t)M_TOT * 128;
    #pragma unroll
    for (int t = 0; t < 4; t++) {
        int o = w * 64 + t * 16 + ln;
        float bv = bout[o];
        float* base = (o < 128) ? (out + o) : (out + hlf + (o - 128));
        #pragma unroll
        for (int i = 0; i < 2; i++) {
            int row = b * SEQ_L + qi * 64 + half * 32 + i * 16 + 4 * quad;
            #pragma unroll
            for (int r = 0; r < 4; r++)
                base[(size_t)(row + r) * 128] = oacc[i][t][r] + bv;
        }
    }
}

extern "C" void kernel_launch(void* const* d_in, const int* in_sizes, int n_in,
                              void* d_out, int out_size, void* d_ws, size_t ws_size,
                              hipStream_t stream) {
    char* ws = (char*)d_ws;
    u16* x_bf    = (u16*)ws;                          // 16384*768  = 25.2 MB
    u16* qk_buf  = x_bf + (size_t)M_TOT * 768;        // 16384*512  = 16.8 MB
    u16* vt_buf  = qk_buf + (size_t)M_TOT * 512;      // 1024*4096  =  8.4 MB
    u16* Wqkv_bf = vt_buf + (size_t)1024 * SEQ_L;     // 589824
    u16* Wout_bf = Wqkv_bf + 589824;                  // 65536
    unsigned char* cmask = (unsigned char*)(Wout_bf + 65536);

    hipLaunchKernelGGL(prep_all, dim3(6480), dim3(256), 0, stream,
                       (const float*)d_in[0], (const float*)d_in[1], (const float*)d_in[2],
                       (const float*)d_in[3], (const float*)d_in[4], (const float*)d_in[5],
                       (const float*)d_in[6], (const float*)d_in[8], d_in[10],
                       x_bf, Wqkv_bf, Wout_bf, cmask);
    hipLaunchKernelGGL(qkv_gemm, dim3(128, 12), dim3(256), 0, stream,
                       x_bf, Wqkv_bf, (const float*)d_in[7], qk_buf, vt_buf);
    hipLaunchKernelGGL(attn_out, dim3(512), dim3(256), 0, stream,
                       qk_buf, vt_buf, Wout_bf, cmask, (const float*)d_in[9], (float*)d_out);
}